// Round 6
// baseline (101.958 us; speedup 1.0000x reference)
//
#include <hip/hip_runtime.h>
#include <hip/hip_bf16.h>

typedef __attribute__((ext_vector_type(8))) short short8;
typedef __attribute__((ext_vector_type(4))) float f32x4;
typedef __attribute__((address_space(1))) const void gvoid_t;
typedef __attribute__((address_space(3))) void lvoid_t;

#define NB 4096   // B
#define DD 256    // D
#define TWOB 8192
#define NMACRO 528u    // upper-triangle 256x256 tiles: sum_{tr=0..31}(32-tr)
#define GSUM_BLOCKS 16
#define NPART 544u     // gsum + macro blocks (8 x 68 exactly)

__device__ __forceinline__ unsigned short f2bf(float f) {
  unsigned int u = __float_as_uint(f);
  u += 0x7fffu + ((u >> 16) & 1u);
  return (unsigned short)(u >> 16);
}
__device__ __forceinline__ float bf2f(unsigned short s) {
  return __uint_as_float(((unsigned int)s) << 16);
}

// ws layout (bytes):
//   [0, 32768)          den[8192] f32 (zeroed by norm blocks 0..31)
//   [65536, 4259840)    znb 8192x256 bf16
//   [4259840, 4276224)  vsum_part[16][4][256] f32
//   [4276224, 4276480)  cnt_part[16][4] int
//   [4276480, 4280576)  ppos[1024] f32
//
// R23: 256x256 macro tiles on the R22 schedule. R22 (counted-vmcnt dist-2,
// 3 buffers, raw s_barrier, XCD swizzle) confirmed the drain theory:
// 108.3 -> 96.65 us. den still ~40 us vs ~10 us pipe floors; remaining
// per-MFMA overheads attacked here by doubling the tile: 8 waves x
// (64x128) per wave, acc=128 regs, __launch_bounds__(512,2) (cap 256 --
// NOT (256,3)-style over-capping, R20's spill trap). LDS 3x(16+16)KB=96KB
// -> 1 block/CU, 8 waves (R21: occupancy-neutral). Per MFMA: LDS reads
// -25%, staged loads -33%, barriers -50%, L2 panel traffic -50%.
// 544 = 8x68 participants, bijective XCD swizzle kept.

// ---------------- kernel A: zero den; normalize -> znb bf16; ppos ---------
__global__ __launch_bounds__(256) void norm_kernel(const float* __restrict__ zi,
                                                   const float* __restrict__ zj,
                                                   float* __restrict__ wsf,
                                                   float* __restrict__ ppos,
                                                   unsigned short* __restrict__ znb) {
  __shared__ float sred[4];
  if (blockIdx.x < 32) wsf[blockIdx.x * 256 + threadIdx.x] = 0.f;
  const int lane = threadIdx.x & 63, wave = threadIdx.x >> 6;
  const int i = blockIdx.x * 4 + wave;

  float4 a = ((const float4*)(zi + (size_t)i * DD))[lane];
  float4 b = ((const float4*)(zj + (size_t)i * DD))[lane];
  float sa = a.x * a.x + a.y * a.y + a.z * a.z + a.w * a.w;
  float sb = b.x * b.x + b.y * b.y + b.z * b.z + b.w * b.w;
  float sab = a.x * b.x + a.y * b.y + a.z * b.z + a.w * b.w;
#pragma unroll
  for (int m = 32; m >= 1; m >>= 1) {
    sa += __shfl_xor(sa, m);
    sb += __shfl_xor(sb, m);
    sab += __shfl_xor(sab, m);
  }
  float ra = 1.0f / fmaxf(sqrtf(sa), 1e-8f);
  float rb = 1.0f / fmaxf(sqrtf(sb), 1e-8f);
  ushort4 oa, ob;
  oa.x = f2bf(a.x * ra); oa.y = f2bf(a.y * ra); oa.z = f2bf(a.z * ra); oa.w = f2bf(a.w * ra);
  ob.x = f2bf(b.x * rb); ob.y = f2bf(b.y * rb); ob.z = f2bf(b.z * rb); ob.w = f2bf(b.w * rb);
  ((ushort4*)(znb + (size_t)i * DD))[lane] = oa;
  ((ushort4*)(znb + (size_t)(i + NB) * DD))[lane] = ob;

  if (lane == 0) sred[wave] = sab * ra * rb;  // exact fp32 pos (row i)
  __syncthreads();
  if (threadIdx.x == 0)
    ppos[blockIdx.x] = sred[0] + sred[1] + sred[2] + sred[3];
}

// ---------------- kernel B: gsum + 256x256 macro den tiles (8 waves) ------
__global__ __launch_bounds__(512, 2) void den_kernel(const int* __restrict__ sf,
                                                     float* __restrict__ wsf,
                                                     const unsigned short* __restrict__ znb,
                                                     float* __restrict__ vsum_part,
                                                     int* __restrict__ cnt_part) {
  __shared__ __align__(16) unsigned short As[3][8192];  // 48 KB (A: 256 rows, 3 bufs)
  __shared__ __align__(16) unsigned short Bs[3][8192];  // 48 KB (B: 256 cols, 3 bufs)

  float* den = wsf;

  const int tid = threadIdx.x;
  const int lane = tid & 63, wave = tid >> 6;  // wave 0..7
  const unsigned t_raw = blockIdx.y * 68u + blockIdx.x;
  if (t_raw >= NPART) return;
  // bijective XCD swizzle: 544 = 8 x 68
  const unsigned t_lin = (t_raw & 7u) * 68u + (t_raw >> 3);

  if (t_lin < GSUM_BLOCKS) {
    // ---- gsum: 256 rows over 8 waves (32 rows each), LDS reduce ----------
    const int b = (int)t_lin;
    const int r0 = b * 256;
    float acc[4][4];
#pragma unroll
    for (int q = 0; q < 4; ++q)
#pragma unroll
      for (int e = 0; e < 4; ++e) acc[q][e] = 0.f;
    int cnt[4] = {0, 0, 0, 0};
    const int rw = r0 + wave * 32;
    for (int k = 0; k < 32; ++k) {
      int row = rw + k;
      int g = sf[row];
      ushort4 v = ((const ushort4*)(znb + (size_t)row * DD))[lane];
      float f0 = bf2f(v.x), f1 = bf2f(v.y), f2 = bf2f(v.z), f3 = bf2f(v.w);
#pragma unroll
      for (int q = 0; q < 4; ++q) {
        bool sel = (g == q);
        acc[q][0] += sel ? f0 : 0.f;
        acc[q][1] += sel ? f1 : 0.f;
        acc[q][2] += sel ? f2 : 0.f;
        acc[q][3] += sel ? f3 : 0.f;
        cnt[q] += sel ? 1 : 0;
      }
    }
    float4* lsd = (float4*)&Bs[0][0];  // 32 x 64 float4 = 32 KB (spans Bs[0..1])
    int* lcnt = (int*)&As[0][0];       // 32 ints
#pragma unroll
    for (int q = 0; q < 4; ++q) {
      float4 t;
      t.x = acc[q][0]; t.y = acc[q][1]; t.z = acc[q][2]; t.w = acc[q][3];
      lsd[(wave * 4 + q) * 64 + lane] = t;
    }
    if (lane == 0) {
#pragma unroll
      for (int q = 0; q < 4; ++q) lcnt[wave * 4 + q] = cnt[q];
    }
    __syncthreads();
    if (tid < 256) {
      int g = tid >> 6, l = tid & 63;
      float4 s = {0.f, 0.f, 0.f, 0.f};
#pragma unroll
      for (int w = 0; w < 8; ++w) {
        float4 sv = lsd[(w * 4 + g) * 64 + l];
        s.x += sv.x; s.y += sv.y; s.z += sv.z; s.w += sv.w;
      }
      ((float4*)(vsum_part + (size_t)(b * 4 + g) * 256))[l] = s;
      if (tid < 4) {
        int ci = 0;
#pragma unroll
        for (int w = 0; w < 8; ++w) ci += lcnt[w * 4 + tid];
        cnt_part[b * 4 + tid] = ci;
      }
    }
    return;
  }

  // ---- one 256x256 macro tile, 8 waves x (64x128) ------------------------
  unsigned t = t_lin - GSUM_BLOCKS;
  unsigned tr = 0;
  while (t >= 32u - tr) { t -= 32u - tr; ++tr; }
  unsigned tc = tr + t;
  const size_t rowbase = (size_t)tr * 256;
  const size_t colbase = (size_t)tc * 256;
  const bool offdiag = (tc > tr);  // block-uniform: add col sums only if off-diag

  const int u = lane >> 3;
  const int cp = (lane & 7) ^ u;
  const int ri = 2 * u + (cp >> 2);
  const int kelem = (cp & 3) * 8;
  const int slot = ((((lane & 1) << 2) | (lane >> 4)) ^ ((lane >> 1) & 7));
  const int fragoff = ((lane & 15) >> 1) * 128 + slot * 16;
  const int wrow = wave >> 1;      // 64-row quarter (0..3)
  const int wcol = wave & 1;       // 128-col half (0..1)

  f32x4 zero = {0.f, 0.f, 0.f, 0.f};
  f32x4 acc[4][8];
#pragma unroll
  for (int i = 0; i < 4; ++i)
#pragma unroll
    for (int j = 0; j < 8; ++j) acc[i][j] = zero;

  // staging: each wave issues 2 A chunks + 2 B chunks (16B/lane each);
  // stage k lands in buffer k%3. 16-row chunks of 1 KB, layout unchanged.
  const unsigned short* gA0 = znb + (rowbase + (2 * wave) * 16 + ri) * DD + kelem;
  const unsigned short* gA1 = gA0 + 16 * DD;
  const unsigned short* gB0 = znb + (colbase + (2 * wave) * 16 + ri) * DD + kelem;
  const unsigned short* gB1 = gB0 + 16 * DD;

  auto stage = [&](int kt, int buf) {
    __builtin_amdgcn_global_load_lds((gvoid_t*)(gA0 + kt * 32), (lvoid_t*)&As[buf][(2 * wave) * 512], 16, 0, 0);
    __builtin_amdgcn_global_load_lds((gvoid_t*)(gA1 + kt * 32), (lvoid_t*)&As[buf][(2 * wave + 1) * 512], 16, 0, 0);
    __builtin_amdgcn_global_load_lds((gvoid_t*)(gB0 + kt * 32), (lvoid_t*)&Bs[buf][(2 * wave) * 512], 16, 0, 0);
    __builtin_amdgcn_global_load_lds((gvoid_t*)(gB1 + kt * 32), (lvoid_t*)&Bs[buf][(2 * wave + 1) * 512], 16, 0, 0);
  };

  // counted-vmcnt pipeline, prefetch distance 2 (4 own loads per stage):
  // top of iter kt: wait vmcnt(4) => own stage(kt) landed (stage(kt+1)'s 4
  // still in flight); s_barrier => ALL waves' stage(kt) landed. stage(kt+2)
  // then overwrites buf (kt-1)%3, which every wave finished reading before
  // this barrier.
  stage(0, 0);
  stage(1, 1);
#pragma unroll
  for (int kt = 0; kt < 8; ++kt) {
    const int buf = kt % 3;
    if (kt < 7) asm volatile("s_waitcnt vmcnt(4)" ::: "memory");
    else        asm volatile("s_waitcnt vmcnt(0)" ::: "memory");
    __builtin_amdgcn_s_barrier();
    asm volatile("" ::: "memory");  // keep stage() below the barrier
    if (kt < 6) stage(kt + 2, (kt + 2) % 3);
    short8 af[4], bfr[8];
#pragma unroll
    for (int mi = 0; mi < 4; ++mi)
      af[mi] = *(const short8*)((const char*)&As[0][0] + buf * 16384 + (wrow * 4 + mi) * 1024 + fragoff);
#pragma unroll
    for (int ni = 0; ni < 8; ++ni)
      bfr[ni] = *(const short8*)((const char*)&Bs[0][0] + buf * 16384 + (wcol * 8 + ni) * 1024 + fragoff);
#pragma unroll
    for (int mi = 0; mi < 4; ++mi)
#pragma unroll
      for (int ni = 0; ni < 8; ++ni)
        acc[mi][ni] = __builtin_amdgcn_mfma_f32_16x16x32_bf16(af[mi], bfr[ni], acc[mi][ni], 0, 0, 0);
  }

  // epilogue: e = exp(2S); row/col sums; combine in LDS; atomics.
  // As[0] safe as scratch: last buf-0 reads (kt=6) completed before kt=7's
  // barrier; kt=7 reads live in buf 1 (disjoint).
  // C layout: col=lane&15, row=(lane>>4)*4+reg.
  float rsum[4][4];
  float csum[8];
#pragma unroll
  for (int mi = 0; mi < 4; ++mi)
#pragma unroll
    for (int r = 0; r < 4; ++r) rsum[mi][r] = 0.f;
#pragma unroll
  for (int ni = 0; ni < 8; ++ni) csum[ni] = 0.f;
#pragma unroll
  for (int mi = 0; mi < 4; ++mi)
#pragma unroll
    for (int ni = 0; ni < 8; ++ni)
#pragma unroll
      for (int r = 0; r < 4; ++r) {
        float e = __expf(2.0f * acc[mi][ni][r]);
        rsum[mi][r] += e;
        csum[ni] += e;
      }
#pragma unroll
  for (int m = 1; m < 16; m <<= 1)
#pragma unroll
    for (int mi = 0; mi < 4; ++mi)
#pragma unroll
      for (int r = 0; r < 4; ++r) rsum[mi][r] += __shfl_xor(rsum[mi][r], m);
#pragma unroll
  for (int m = 16; m < 64; m <<= 1)
#pragma unroll
    for (int ni = 0; ni < 8; ++ni) csum[ni] += __shfl_xor(csum[ni], m);

  float* Lr = (float*)&As[0][0];  // [2][256] indexed by wcol (2 KB)
  float* Lc = Lr + 512;           // [4][256] indexed by wrow (4 KB)
  if ((lane & 15) == 0) {
    int h = lane >> 4;
#pragma unroll
    for (int mi = 0; mi < 4; ++mi)
#pragma unroll
      for (int r = 0; r < 4; ++r)
        Lr[wcol * 256 + wrow * 64 + mi * 16 + h * 4 + r] = rsum[mi][r];
  }
  if (lane < 16) {
#pragma unroll
    for (int ni = 0; ni < 8; ++ni)
      Lc[wrow * 256 + wcol * 128 + ni * 16 + lane] = csum[ni];
  }
  __syncthreads();
  if (tid < 256) {
    unsafeAtomicAdd(&den[rowbase + tid], Lr[tid] + Lr[256 + tid]);
  } else if (offdiag) {
    int cc = tid - 256;
    unsafeAtomicAdd(&den[colbase + cc],
                    Lc[cc] + Lc[256 + cc] + Lc[512 + cc] + Lc[768 + cc]);
  }
}

// ---------------- kernel C: tail (1 block x 1024) -------------------------
__global__ __launch_bounds__(1024) void tail_kernel(const float* __restrict__ wsf,
                                                    const float* __restrict__ vsum_part,
                                                    const int* __restrict__ cnt_part,
                                                    const float* __restrict__ ppos,
                                                    float* __restrict__ out) {
  __shared__ float sred[48];
  const float* den = wsf;
  const int tid = threadIdx.x;
  const int lane = tid & 63, wave = tid >> 6;  // 16 waves

  const float e2 = __expf(2.0f);
  float ls = 0.f;
#pragma unroll
  for (int k = 0; k < 8; ++k) ls += __logf(den[k * 1024 + tid] - e2);
#pragma unroll
  for (int m = 32; m >= 1; m >>= 1) ls += __shfl_xor(ls, m);
  if (lane == 0) sred[wave] = ls;

  float pp = ppos[tid];
#pragma unroll
  for (int m = 32; m >= 1; m >>= 1) pp += __shfl_xor(pp, m);
  if (lane == 0) sred[16 + wave] = pp;

  // group col-sums: thread t -> g = t>>8, col = t&255 (g wave-uniform)
  {
    int g = tid >> 8, col = tid & 255;
    float v = 0.f;
#pragma unroll
    for (int b = 0; b < 16; ++b) v += vsum_part[(size_t)(b * 4 + g) * 256 + col];
    float gp = v * v;
#pragma unroll
    for (int m = 32; m >= 1; m >>= 1) gp += __shfl_xor(gp, m);
    if (lane == 0) sred[32 + wave] = gp;  // wave w -> group w>>2
  }
  __syncthreads();
  if (tid == 0) {
    float lsum = 0.f, psum = 0.f;
#pragma unroll
    for (int w = 0; w < 16; ++w) { lsum += sred[w]; psum += sred[16 + w]; }
    float contrastive = (lsum - 4.0f * psum) / (float)TWOB;
    float fsum = 0.f;
    int uniq = 0;
#pragma unroll
    for (int q = 0; q < 4; ++q) {
      int ci = 0;
#pragma unroll
      for (int b = 0; b < 16; ++b) ci += cnt_part[b * 4 + q];
      float gsq = sred[32 + q * 4] + sred[33 + q * 4] + sred[34 + q * 4] + sred[35 + q * 4];
      float cf = (float)ci;
      if (ci > 0) uniq++;
      if (ci > 1) fsum += gsq / (cf * (cf - 1.0f));
    }
    out[0] = contrastive + 0.1f * (fsum / (uniq > 0 ? (float)uniq : 1.0f));
  }
}

extern "C" void kernel_launch(void* const* d_in, const int* in_sizes, int n_in,
                              void* d_out, int out_size, void* d_ws, size_t ws_size,
                              hipStream_t stream) {
  const float* zi = (const float*)d_in[0];
  const float* zj = (const float*)d_in[1];
  const int* sf = (const int*)d_in[2];
  float* out = (float*)d_out;
  char* ws = (char*)d_ws;
  float* wsf = (float*)ws;                              // den
  unsigned short* znb = (unsigned short*)(ws + 65536);  // 8192x256 bf16 (4MB)
  float* vsum_part = (float*)(ws + 4259840);            // 16x4x256 f32
  int* cnt_part = (int*)(ws + 4276224);                 // 16x4 int
  float* ppos = (float*)(ws + 4276480);                 // 1024 f32

  hipLaunchKernelGGL(norm_kernel, dim3(1024), dim3(256), 0, stream, zi, zj, wsf, ppos, znb);
  hipLaunchKernelGGL(den_kernel, dim3(68, 8), dim3(512), 0, stream,
                     sf, wsf, znb, vsum_part, cnt_part);
  hipLaunchKernelGGL(tail_kernel, dim3(1), dim3(1024), 0, stream,
                     wsf, vsum_part, cnt_part, ppos, out);
}